// Round 3
// baseline (9370.847 us; speedup 1.0000x reference)
//
#include <hip/hip_runtime.h>

// CustomLSTM on MI355X: persistent cooperative kernel, both layers pipelined,
// bf16 MFMA (16x16x32), weights LDS-resident, hand-rolled grid barrier.

#define NBLK 256
#define TPB  512
#define T_   512
#define HS_OFF 33554432   // outputs floats
#define CS_OFF 33685504   // HS_OFF + 2*64*1024

typedef float  f32x4  __attribute__((ext_vector_type(4)));
typedef short  bf16x8 __attribute__((ext_vector_type(8)));

// ---- workspace byte offsets ----
#define WS_CTR  0u
#define WS_W    4096u           // 4 * (4096*1024) bf16 = 32 MiB (permuted, [p][k])
#define WS_BIAS 33558528u       // 2*4096 f32
#define WS_XB   33591296u       // [T][B][D] bf16 = 64 MiB
#define WS_H0   100700160u      // ring: 2 * [64][1024] bf16
#define WS_H1   100962304u
#define WS_TOT  101224448u

__device__ __forceinline__ unsigned short f2bf(float f) {
  union { float f; unsigned u; } v; v.f = f;
  return (unsigned short)((v.u + 0x7FFFu + ((v.u >> 16) & 1u)) >> 16);
}
__device__ __forceinline__ float fsig(float x) { return 1.0f / (1.0f + __expf(-x)); }
__device__ __forceinline__ float ftanh(float x) {
  x = fminf(15.0f, fmaxf(-15.0f, x));
  float e = __expf(2.0f * x);
  return (e - 1.0f) / (e + 1.0f);
}

// Permute+transpose+bf16 the 4 weight matrices: out[m][p][k] = bf16(W_m[k][orig(p)]),
// orig(p) = (p&3)*1024 + (p>>2)  (p = 4*j + gate). 64x64 tiles via LDS.
__global__ void kw(const float* __restrict__ Wx0, const float* __restrict__ Wh0,
                   const float* __restrict__ Wx1, const float* __restrict__ Wh1,
                   unsigned short* __restrict__ wp) {
  __shared__ float tile[64][65];
  int tb = blockIdx.x;
  int m  = tb >> 10;
  int kt = (tb >> 6) & 15;
  int nt = tb & 63;
  const float* W = (m == 0) ? Wx0 : (m == 1) ? Wh0 : (m == 2) ? Wx1 : Wh1;
  unsigned short* O = wp + (size_t)m * 4194304u;
  int k0 = kt * 64, n0 = nt * 64;
  int tx = threadIdx.x & 63, tg = threadIdx.x >> 6;
  for (int r = tg; r < 64; r += 4)
    tile[r][tx] = W[(size_t)(k0 + r) * 4096 + n0 + tx];
  __syncthreads();
  for (int r = tg; r < 64; r += 4) {
    int n = n0 + r;
    int p = ((n & 1023) << 2) | (n >> 10);
    O[(size_t)p * 1024 + k0 + tx] = f2bf(tile[tx][r]);
  }
}

// x [B][T][D] f32 -> xb [T*B][D] bf16 (row = t*64+b)
__global__ void kx(const float* __restrict__ x, unsigned short* __restrict__ xb) {
  int row = blockIdx.x;
  int t = row >> 6, b = row & 63;
  const float4* src = (const float4*)(x + ((size_t)b * 512 + t) * 1024);
  float4 f = src[threadIdx.x];
  ushort4 o; o.x = f2bf(f.x); o.y = f2bf(f.y); o.z = f2bf(f.z); o.w = f2bf(f.w);
  ((ushort4*)(xb + (size_t)row * 1024))[threadIdx.x] = o;
}

// bias permute + prime ring slot 1 with h0 initial states (bf16)
__global__ void kmisc(const float* __restrict__ b0, const float* __restrict__ b1,
                      const float* __restrict__ h0in,
                      float* __restrict__ biasP,
                      unsigned short* __restrict__ h0r, unsigned short* __restrict__ h1r) {
  int idx = blockIdx.x * 256 + threadIdx.x;
  if (idx < 8192) {
    int layer = idx >> 12, p = idx & 4095;
    int orig = (p & 3) * 1024 + (p >> 2);
    biasP[idx] = (layer ? b1 : b0)[orig];
  } else if (idx < 139264) {
    int e = idx - 8192;
    int layer = e >> 16, o = e & 65535;
    unsigned short v = f2bf(h0in[layer * 65536 + o]);
    if (layer) h1r[65536 + o] = v; else h0r[65536 + o] = v;
  }
}

// Persistent cooperative kernel. 256 blocks x 512 threads (8 waves).
// Wave w: rows 16*(w&3), K-half (w>>2)*512, finalizes layer (w>>2).
__global__ void __launch_bounds__(TPB, 2)
klstm(const float* __restrict__ c0_in,
      const unsigned short* __restrict__ wp,
      const float* __restrict__ biasP,
      const unsigned short* __restrict__ xb,
      unsigned short* __restrict__ h0ring,
      unsigned short* __restrict__ h1ring,
      unsigned* __restrict__ ctr,
      float* __restrict__ out) {
  extern __shared__ char smem[];           // 128KB weights + 8KB reduce
  float* red = (float*)(smem + 131072);
  const int tid = threadIdx.x;
  const int w   = tid >> 6;
  const int l   = tid & 63;
  const int bid = blockIdx.x;
  const int n0  = bid * 16;
  const int layer = w >> 2;
  const int rbase = (w & 3) * 16;
  const int khalf = (w >> 2) * 512;

  // stage 4 weight slices (16 cols x 1024 K bf16 each) into LDS, XOR-swizzled
  for (int m = 0; m < 4; ++m) {
    const char* src = (const char*)(wp + (size_t)m * 4194304u + (size_t)n0 * 1024u);
    char* dst = smem + m * 32768;
    for (int i = tid; i < 2048; i += TPB) {
      int sb = i << 4;
      int c  = sb >> 11;
      int kb = sb & 2047;
      *(uint4*)(dst + (c << 11) + (kb ^ ((c & 7) << 4))) = *(const uint4*)(src + sb);
    }
  }

  const int jg = bid * 4 + ((l & 15) >> 2);   // global h column
  const int p  = n0 + (l & 15);
  const float biasv = biasP[layer * 4096 + p];
  const int qb = l & ~3;

  float cr[4];
  #pragma unroll
  for (int v = 0; v < 4; ++v) {
    int row = rbase + (l >> 4) * 4 + v;
    cr[v] = c0_in[layer * 65536 + row * 1024 + jg];
  }
  __syncthreads();

  const int abase = (rbase + (l & 15)) * 1024 + khalf + (l >> 4) * 8;
  const int lb0 = (l & 15) << 11;
  const int kb2 = khalf * 2 + (l >> 4) * 16;
  const int swz = (l & 7) << 4;

  for (int k = 0; k <= T_; ++k) {
    const unsigned short* xt  = xb + (size_t)((k < T_) ? k : (T_ - 1)) * 65536u;
    const unsigned short* h0p = h0ring + ((k + 1) & 1) * 65536;
    const unsigned short* h1p = h1ring + (k & 1) * 65536;

    f32x4 acc0 = {0.f, 0.f, 0.f, 0.f};
    f32x4 acc1 = {0.f, 0.f, 0.f, 0.f};
    #pragma unroll
    for (int kk = 0; kk < 16; ++kk) {
      const int ae = abase + kk * 32;
      bf16x8 ax  = *(const bf16x8*)(xt  + ae);
      bf16x8 ah0 = *(const bf16x8*)(h0p + ae);
      bf16x8 ah1 = *(const bf16x8*)(h1p + ae);
      const int bo = lb0 + ((kb2 + kk * 64) ^ swz);
      bf16x8 bx0 = *(const bf16x8*)(smem + bo);
      bf16x8 bh0 = *(const bf16x8*)(smem + 32768 + bo);
      bf16x8 bx1 = *(const bf16x8*)(smem + 65536 + bo);
      bf16x8 bh1 = *(const bf16x8*)(smem + 98304 + bo);
      acc0 = __builtin_amdgcn_mfma_f32_16x16x32_bf16(ax,  bx0, acc0, 0, 0, 0);
      acc0 = __builtin_amdgcn_mfma_f32_16x16x32_bf16(ah0, bh0, acc0, 0, 0, 0);
      acc1 = __builtin_amdgcn_mfma_f32_16x16x32_bf16(ah0, bx1, acc1, 0, 0, 0);
      acc1 = __builtin_amdgcn_mfma_f32_16x16x32_bf16(ah1, bh1, acc1, 0, 0, 0);
    }

    { // publish the other layer's partial for the partner wave
      float* rb = red + (size_t)(w * 64 + l) * 4;
      f32x4 other = layer ? acc0 : acc1;
      #pragma unroll
      for (int v = 0; v < 4; ++v) rb[v] = other[v];
    }
    __syncthreads();

    f32x4 g = layer ? acc1 : acc0;
    {
      const int pw = layer ? (w - 4) : (w + 4);
      const float* rb = red + (size_t)(pw * 64 + l) * 4;
      #pragma unroll
      for (int v = 0; v < 4; ++v) g[v] += rb[v];
    }

    const bool active = layer ? (k >= 1) : (k < T_);
    if (active) {
      unsigned short* hw = layer ? (h1ring + ((k + 1) & 1) * 65536)
                                 : (h0ring + (k & 1) * 65536);
      #pragma unroll
      for (int v = 0; v < 4; ++v) {
        float gv = g[v] + biasv;
        float gi = __shfl(gv, qb);
        float gf = __shfl(gv, qb | 1);
        float gn = __shfl(gv, qb | 2);
        float go = __shfl(gv, qb | 3);
        float i_ = fsig(gi), f_ = fsig(gf), n_ = ftanh(gn), o_ = fsig(go);
        float c = f_ * cr[v] + i_ * n_;
        cr[v] = c;
        float h = o_ * ftanh(c);
        if ((l & 3) == 0) {
          int row = rbase + (l >> 4) * 4 + v;
          __hip_atomic_store(&hw[row * 1024 + jg], f2bf(h),
                             __ATOMIC_RELAXED, __HIP_MEMORY_SCOPE_AGENT);
          if (layer) {
            out[(size_t)row * 524288u + (size_t)(k - 1) * 1024u + jg] = h;
            if (k == T_) out[HS_OFF + 65536 + row * 1024 + jg] = h;
          } else {
            if (k == T_ - 1) out[HS_OFF + row * 1024 + jg] = h;
          }
        }
      }
    }

    if (k < T_) {   // grid barrier (monotonic per-step counter, bounded spin)
      __syncthreads();
      if (tid == 0) {
        unsigned* a = &ctr[k];
        __hip_atomic_fetch_add(a, 1u, __ATOMIC_RELAXED, __HIP_MEMORY_SCOPE_AGENT);
        unsigned spins = 0;
        while (__hip_atomic_load(a, __ATOMIC_RELAXED, __HIP_MEMORY_SCOPE_AGENT) < (unsigned)NBLK) {
          __builtin_amdgcn_s_sleep(2);
          if (++spins > 67108864u) break;   // safety: never wedge the GPU
        }
        __builtin_amdgcn_fence(__ATOMIC_ACQUIRE, "agent");
      }
      __syncthreads();
    }
  }

  // final cell states
  #pragma unroll
  for (int v = 0; v < 4; ++v) {
    if ((l & 3) == 0) {
      int row = rbase + (l >> 4) * 4 + v;
      out[CS_OFF + layer * 65536 + row * 1024 + jg] = cr[v];
    }
  }
}

extern "C" void kernel_launch(void* const* d_in, const int* in_sizes, int n_in,
                              void* d_out, int out_size, void* d_ws, size_t ws_size,
                              hipStream_t stream) {
  const float* x   = (const float*)d_in[0];
  const float* h0  = (const float*)d_in[1];
  const float* c0  = (const float*)d_in[2];
  const float* Wx0 = (const float*)d_in[3];
  const float* Wh0 = (const float*)d_in[4];
  const float* b0  = (const float*)d_in[5];
  const float* Wx1 = (const float*)d_in[6];
  const float* Wh1 = (const float*)d_in[7];
  const float* b1  = (const float*)d_in[8];
  float* out = (float*)d_out;
  char* ws = (char*)d_ws;
  if (ws_size < (size_t)WS_TOT) return;   // workspace too small -> fail loudly

  unsigned* ctr       = (unsigned*)(ws + WS_CTR);
  unsigned short* wp  = (unsigned short*)(ws + WS_W);
  float* biasP        = (float*)(ws + WS_BIAS);
  unsigned short* xbp = (unsigned short*)(ws + WS_XB);
  unsigned short* h0r = (unsigned short*)(ws + WS_H0);
  unsigned short* h1r = (unsigned short*)(ws + WS_H1);

  (void)hipMemsetAsync(ctr, 0, 4096, stream);
  hipLaunchKernelGGL(kw,    dim3(4096),  dim3(256), 0, stream, Wx0, Wh0, Wx1, Wh1, wp);
  hipLaunchKernelGGL(kx,    dim3(32768), dim3(256), 0, stream, x, xbp);
  hipLaunchKernelGGL(kmisc, dim3(544),   dim3(256), 0, stream, b0, b1, h0, biasP, h0r, h1r);

  (void)hipFuncSetAttribute((const void*)klstm, hipFuncAttributeMaxDynamicSharedMemorySize, 139264);
  const float* c0a = c0; const unsigned short* wpa = wp; const float* bpa = biasP;
  const unsigned short* xba = xbp; unsigned short* h0a = h0r; unsigned short* h1a = h1r;
  unsigned* ca = ctr; float* oa = out;
  void* args[] = {&c0a, &wpa, &bpa, &xba, &h0a, &h1a, &ca, &oa};
  hipError_t e = hipLaunchCooperativeKernel((const void*)klstm, dim3(NBLK), dim3(TPB),
                                            args, 139264, stream);
  if (e != hipSuccess) {
    hipLaunchKernelGGL(klstm, dim3(NBLK), dim3(TPB), 139264, stream,
                       c0a, wpa, bpa, xba, h0a, h1a, ca, oa);
  }
}

// Round 4
// 8059.205 us; speedup vs baseline: 1.1628x; 1.1628x over previous
//
#include <hip/hip_runtime.h>

// CustomLSTM on MI355X: persistent cooperative kernel, both layers pipelined,
// bf16 MFMA (16x16x32), weights LDS-resident, hierarchical tree grid barrier.

#define NBLK 256
#define TPB  512
#define T_   512
#define HS_OFF 33554432   // outputs floats
#define CS_OFF 33685504   // HS_OFF + 2*64*1024

typedef float  f32x4  __attribute__((ext_vector_type(4)));
typedef short  bf16x8 __attribute__((ext_vector_type(8)));

// ---- workspace byte offsets ----
#define WS_CTR  0u              // 32 KB: gctr[8][512] u32 | rctr[512] | flag[512]
#define WS_W    32768u          // 4 * (4096*1024) bf16 = 32 MiB (permuted, [p][k])
#define WS_BIAS 33587200u       // 2*4096 f32
#define WS_XB   33619968u       // [T][B][D] bf16 = 64 MiB
#define WS_H0   100728832u      // ring: 2 * [64][1024] bf16
#define WS_H1   100990976u
#define WS_TOT  101253120u

__device__ __forceinline__ unsigned short f2bf(float f) {
  union { float f; unsigned u; } v; v.f = f;
  return (unsigned short)((v.u + 0x7FFFu + ((v.u >> 16) & 1u)) >> 16);
}
__device__ __forceinline__ float fsig(float x) { return 1.0f / (1.0f + __expf(-x)); }
__device__ __forceinline__ float ftanh(float x) {
  x = fminf(15.0f, fmaxf(-15.0f, x));
  float e = __expf(2.0f * x);
  return (e - 1.0f) / (e + 1.0f);
}

// Permute+transpose+bf16 the 4 weight matrices: out[m][p][k] = bf16(W_m[k][orig(p)]),
// orig(p) = (p&3)*1024 + (p>>2)  (p = 4*j + gate). 64x64 tiles via LDS.
__global__ void kw(const float* __restrict__ Wx0, const float* __restrict__ Wh0,
                   const float* __restrict__ Wx1, const float* __restrict__ Wh1,
                   unsigned short* __restrict__ wp) {
  __shared__ float tile[64][65];
  int tb = blockIdx.x;
  int m  = tb >> 10;
  int kt = (tb >> 6) & 15;
  int nt = tb & 63;
  const float* W = (m == 0) ? Wx0 : (m == 1) ? Wh0 : (m == 2) ? Wx1 : Wh1;
  unsigned short* O = wp + (size_t)m * 4194304u;
  int k0 = kt * 64, n0 = nt * 64;
  int tx = threadIdx.x & 63, tg = threadIdx.x >> 6;
  for (int r = tg; r < 64; r += 4)
    tile[r][tx] = W[(size_t)(k0 + r) * 4096 + n0 + tx];
  __syncthreads();
  for (int r = tg; r < 64; r += 4) {
    int n = n0 + r;
    int p = ((n & 1023) << 2) | (n >> 10);
    O[(size_t)p * 1024 + k0 + tx] = f2bf(tile[tx][r]);
  }
}

// x [B][T][D] f32 -> xb [T*B][D] bf16 (row = t*64+b)
__global__ void kx(const float* __restrict__ x, unsigned short* __restrict__ xb) {
  int row = blockIdx.x;
  int t = row >> 6, b = row & 63;
  const float4* src = (const float4*)(x + ((size_t)b * 512 + t) * 1024);
  float4 f = src[threadIdx.x];
  ushort4 o; o.x = f2bf(f.x); o.y = f2bf(f.y); o.z = f2bf(f.z); o.w = f2bf(f.w);
  ((ushort4*)(xb + (size_t)row * 1024))[threadIdx.x] = o;
}

// bias permute + prime ring slot 1 with h0 initial states (bf16)
__global__ void kmisc(const float* __restrict__ b0, const float* __restrict__ b1,
                      const float* __restrict__ h0in,
                      float* __restrict__ biasP,
                      unsigned short* __restrict__ h0r, unsigned short* __restrict__ h1r) {
  int idx = blockIdx.x * 256 + threadIdx.x;
  if (idx < 8192) {
    int layer = idx >> 12, p = idx & 4095;
    int orig = (p & 3) * 1024 + (p >> 2);
    biasP[idx] = (layer ? b1 : b0)[orig];
  } else if (idx < 139264) {
    int e = idx - 8192;
    int layer = e >> 16, o = e & 65535;
    unsigned short v = f2bf(h0in[layer * 65536 + o]);
    if (layer) h1r[65536 + o] = v; else h0r[65536 + o] = v;
  }
}

// Persistent cooperative kernel. 256 blocks x 512 threads (8 waves).
// Wave w: rows 16*(w&3), K-half (w>>2)*512, finalizes layer (w>>2).
__global__ void __launch_bounds__(TPB, 2)
klstm(const float* __restrict__ c0_in,
      const unsigned short* __restrict__ wp,
      const float* __restrict__ biasP,
      const unsigned short* __restrict__ xb,
      unsigned short* __restrict__ h0ring,
      unsigned short* __restrict__ h1ring,
      unsigned* __restrict__ ctrbase,
      float* __restrict__ out) {
  extern __shared__ char smem[];           // 128KB weights + 8KB reduce
  float* red = (float*)(smem + 131072);
  unsigned* gctr = ctrbase;                // [8][512]
  unsigned* rctr = ctrbase + 4096;         // [512]
  unsigned* flag = ctrbase + 4608;         // [512]
  const int tid = threadIdx.x;
  const int w   = tid >> 6;
  const int l   = tid & 63;
  const int bid = blockIdx.x;
  const int n0  = bid * 16;
  const int layer = w >> 2;
  const int rbase = (w & 3) * 16;
  const int khalf = (w >> 2) * 512;

  // stage 4 weight slices (16 cols x 1024 K bf16 each) into LDS, XOR-swizzled
  for (int m = 0; m < 4; ++m) {
    const char* src = (const char*)(wp + (size_t)m * 4194304u + (size_t)n0 * 1024u);
    char* dst = smem + m * 32768;
    for (int i = tid; i < 2048; i += TPB) {
      int sb = i << 4;
      int c  = sb >> 11;
      int kb = sb & 2047;
      *(uint4*)(dst + (c << 11) + (kb ^ ((c & 7) << 4))) = *(const uint4*)(src + sb);
    }
  }

  const int jg = bid * 4 + ((l & 15) >> 2);   // global h column
  const int p  = n0 + (l & 15);
  const float biasv = biasP[layer * 4096 + p];
  const int qb = l & ~3;

  float cr[4];
  #pragma unroll
  for (int v = 0; v < 4; ++v) {
    int row = rbase + (l >> 4) * 4 + v;
    cr[v] = c0_in[layer * 65536 + row * 1024 + jg];
  }
  __syncthreads();

  const int abase = (rbase + (l & 15)) * 1024 + khalf + (l >> 4) * 8;
  const int lb0 = (l & 15) << 11;
  const int kb2 = khalf * 2 + (l >> 4) * 16;
  const int swz = (l & 7) << 4;

  for (int k = 0; k <= T_; ++k) {
    const unsigned short* xt  = xb + (size_t)((k < T_) ? k : (T_ - 1)) * 65536u;
    const unsigned short* h0p = h0ring + ((k + 1) & 1) * 65536;
    const unsigned short* h1p = h1ring + (k & 1) * 65536;

    f32x4 acc0 = {0.f, 0.f, 0.f, 0.f};
    f32x4 acc1 = {0.f, 0.f, 0.f, 0.f};
    #pragma unroll
    for (int kk = 0; kk < 16; ++kk) {
      const int ae = abase + kk * 32;
      bf16x8 ax  = *(const bf16x8*)(xt  + ae);
      bf16x8 ah0 = *(const bf16x8*)(h0p + ae);
      bf16x8 ah1 = *(const bf16x8*)(h1p + ae);
      const int bo = lb0 + ((kb2 + kk * 64) ^ swz);
      bf16x8 bx0 = *(const bf16x8*)(smem + bo);
      bf16x8 bh0 = *(const bf16x8*)(smem + 32768 + bo);
      bf16x8 bx1 = *(const bf16x8*)(smem + 65536 + bo);
      bf16x8 bh1 = *(const bf16x8*)(smem + 98304 + bo);
      acc0 = __builtin_amdgcn_mfma_f32_16x16x32_bf16(ax,  bx0, acc0, 0, 0, 0);
      acc0 = __builtin_amdgcn_mfma_f32_16x16x32_bf16(ah0, bh0, acc0, 0, 0, 0);
      acc1 = __builtin_amdgcn_mfma_f32_16x16x32_bf16(ah0, bx1, acc1, 0, 0, 0);
      acc1 = __builtin_amdgcn_mfma_f32_16x16x32_bf16(ah1, bh1, acc1, 0, 0, 0);
    }

    { // publish the other layer's partial for the partner wave
      float* rb = red + (size_t)(w * 64 + l) * 4;
      f32x4 other = layer ? acc0 : acc1;
      #pragma unroll
      for (int v = 0; v < 4; ++v) rb[v] = other[v];
    }
    __syncthreads();

    f32x4 g = layer ? acc1 : acc0;
    {
      const int pw = layer ? (w - 4) : (w + 4);
      const float* rb = red + (size_t)(pw * 64 + l) * 4;
      #pragma unroll
      for (int v = 0; v < 4; ++v) g[v] += rb[v];
    }

    const bool active = layer ? (k >= 1) : (k < T_);
    float hv[4];
    if (active) {
      unsigned short* hw = layer ? (h1ring + ((k + 1) & 1) * 65536)
                                 : (h0ring + (k & 1) * 65536);
      #pragma unroll
      for (int v = 0; v < 4; ++v) {
        float gv = g[v] + biasv;
        float gi = __shfl(gv, qb);
        float gf = __shfl(gv, qb | 1);
        float gn = __shfl(gv, qb | 2);
        float go = __shfl(gv, qb | 3);
        float i_ = fsig(gi), f_ = fsig(gf), n_ = ftanh(gn), o_ = fsig(go);
        float c = f_ * cr[v] + i_ * n_;
        cr[v] = c;
        float h = o_ * ftanh(c);
        hv[v] = h;
        if ((l & 3) == 0) {
          int row = rbase + (l >> 4) * 4 + v;
          __hip_atomic_store(&hw[row * 1024 + jg], f2bf(h),
                             __ATOMIC_RELAXED, __HIP_MEMORY_SCOPE_AGENT);
        }
      }
    }

    // ---- barrier arrival (after h-ring stores are drained block-wide) ----
    if (k < T_) {
      __syncthreads();                      // drains vmcnt(0): h stores at MALL
      if (tid == 0) {
        unsigned old = __hip_atomic_fetch_add(&gctr[(bid >> 5) * 512 + k], 1u,
                                              __ATOMIC_RELAXED, __HIP_MEMORY_SCOPE_AGENT);
        if (old == 31u) {
          unsigned oldr = __hip_atomic_fetch_add(&rctr[k], 1u,
                                                 __ATOMIC_RELAXED, __HIP_MEMORY_SCOPE_AGENT);
          if (oldr == 7u)
            __hip_atomic_store(&flag[k], 1u, __ATOMIC_RELAXED, __HIP_MEMORY_SCOPE_AGENT);
        }
      }
    }

    // ---- out stores overlapped with barrier propagation ----
    if (active && (l & 3) == 0) {
      #pragma unroll
      for (int v = 0; v < 4; ++v) {
        int row = rbase + (l >> 4) * 4 + v;
        if (layer) {
          out[(size_t)row * 524288u + (size_t)(k - 1) * 1024u + jg] = hv[v];
          if (k == T_) out[HS_OFF + 65536 + row * 1024 + jg] = hv[v];
        } else {
          if (k == T_ - 1) out[HS_OFF + row * 1024 + jg] = hv[v];
        }
      }
    }

    // ---- barrier wait + acquire (L2 inv so next step's h loads are fresh) ----
    if (k < T_) {
      if (tid == 0) {
        unsigned spins = 0;
        while (__hip_atomic_load(&flag[k], __ATOMIC_RELAXED, __HIP_MEMORY_SCOPE_AGENT) == 0u) {
          __builtin_amdgcn_s_sleep(1);
          if (++spins > 67108864u) break;   // safety: never wedge the GPU
        }
        __builtin_amdgcn_fence(__ATOMIC_ACQUIRE, "agent");
      }
      __syncthreads();
    }
  }

  // final cell states
  #pragma unroll
  for (int v = 0; v < 4; ++v) {
    if ((l & 3) == 0) {
      int row = rbase + (l >> 4) * 4 + v;
      out[CS_OFF + layer * 65536 + row * 1024 + jg] = cr[v];
    }
  }
}

extern "C" void kernel_launch(void* const* d_in, const int* in_sizes, int n_in,
                              void* d_out, int out_size, void* d_ws, size_t ws_size,
                              hipStream_t stream) {
  const float* x   = (const float*)d_in[0];
  const float* h0  = (const float*)d_in[1];
  const float* c0  = (const float*)d_in[2];
  const float* Wx0 = (const float*)d_in[3];
  const float* Wh0 = (const float*)d_in[4];
  const float* b0  = (const float*)d_in[5];
  const float* Wx1 = (const float*)d_in[6];
  const float* Wh1 = (const float*)d_in[7];
  const float* b1  = (const float*)d_in[8];
  float* out = (float*)d_out;
  char* ws = (char*)d_ws;
  if (ws_size < (size_t)WS_TOT) return;   // workspace too small -> fail loudly

  unsigned* ctr       = (unsigned*)(ws + WS_CTR);
  unsigned short* wp  = (unsigned short*)(ws + WS_W);
  float* biasP        = (float*)(ws + WS_BIAS);
  unsigned short* xbp = (unsigned short*)(ws + WS_XB);
  unsigned short* h0r = (unsigned short*)(ws + WS_H0);
  unsigned short* h1r = (unsigned short*)(ws + WS_H1);

  (void)hipMemsetAsync(ctr, 0, 32768, stream);
  hipLaunchKernelGGL(kw,    dim3(4096),  dim3(256), 0, stream, Wx0, Wh0, Wx1, Wh1, wp);
  hipLaunchKernelGGL(kx,    dim3(32768), dim3(256), 0, stream, x, xbp);
  hipLaunchKernelGGL(kmisc, dim3(544),   dim3(256), 0, stream, b0, b1, h0, biasP, h0r, h1r);

  (void)hipFuncSetAttribute((const void*)klstm, hipFuncAttributeMaxDynamicSharedMemorySize, 139264);
  const float* c0a = c0; const unsigned short* wpa = wp; const float* bpa = biasP;
  const unsigned short* xba = xbp; unsigned short* h0a = h0r; unsigned short* h1a = h1r;
  unsigned* ca = ctr; float* oa = out;
  void* args[] = {&c0a, &wpa, &bpa, &xba, &h0a, &h1a, &ca, &oa};
  hipError_t e = hipLaunchCooperativeKernel((const void*)klstm, dim3(NBLK), dim3(TPB),
                                            args, 139264, stream);
  if (e != hipSuccess) {
    hipLaunchKernelGGL(klstm, dim3(NBLK), dim3(TPB), 139264, stream,
                       c0a, wpa, bpa, xba, h0a, h1a, ca, oa);
  }
}